// Round 18
// baseline (711.029 us; speedup 1.0000x reference)
//
#include <hip/hip_runtime.h>
#include <math.h>

#define DIMC 128
#define FINC 78
#define REPW 1152        // 9 * 128
#define SCAN_TILE 1024   // elements per scan tile (256 threads x 4)

typedef __attribute__((ext_vector_type(8))) short short8x;
typedef __attribute__((ext_vector_type(4))) float f32x4;
typedef unsigned int u32;
typedef const __attribute__((address_space(1))) u32* gas_u32p;
typedef __attribute__((address_space(3))) u32* las_u32p;

__device__ inline float b2f(unsigned short u) {
    union { unsigned int i; float f; } v; v.i = ((unsigned int)u) << 16; return v.f;
}
__device__ inline unsigned short f2b(float f) {
    union { float f; unsigned int i; } v; v.f = f;
    unsigned int r = (v.i + 0x7FFFu + ((v.i >> 16) & 1u)) >> 16;
    return (unsigned short)r;
}

// 16B global -> LDS DMA (LDS dest = wave-uniform base + lane*16; our dest is linear in tid).
__device__ __forceinline__ void gld16(const void* g, void* l) {
    __builtin_amdgcn_global_load_lds((gas_u32p)g, (las_u32p)l, 16, 0, 0);
}

// ---------------- setup kernels ----------------

__global__ void k_fill_int(int* __restrict__ p, int v, int n) {
    int i = blockIdx.x * blockDim.x + threadIdx.x;
    if (i < n) p[i] = v;
}

__global__ void k_fill(float* __restrict__ p, float v, int n) {
    int i = blockIdx.x * blockDim.x + threadIdx.x;
    if (i < n) p[i] = v;
}

__global__ void k_count(const int* __restrict__ dst, int* __restrict__ cnt, int E) {
    int e = blockIdx.x * blockDim.x + threadIdx.x;
    if (e < E) atomicAdd(&cnt[dst[e]], 1);
}

__launch_bounds__(256)
__global__ void k_tilesum(const int* __restrict__ cnt, int* __restrict__ tileSum, int N) {
    __shared__ int red[256];
    int base = blockIdx.x * SCAN_TILE;
    int s = 0;
    for (int i = threadIdx.x; i < SCAN_TILE; i += 256) {
        int idx = base + i;
        if (idx < N) s += cnt[idx];
    }
    red[threadIdx.x] = s;
    __syncthreads();
    for (int d = 128; d > 0; d >>= 1) {
        if (threadIdx.x < d) red[threadIdx.x] += red[threadIdx.x + d];
        __syncthreads();
    }
    if (threadIdx.x == 0) tileSum[blockIdx.x] = red[0];
}

__launch_bounds__(256)
__global__ void k_tilescan(const int* __restrict__ tileSum, int* __restrict__ tileOff,
                           int* __restrict__ rowptr, int T, int N) {
    __shared__ int sh[256];
    int t = threadIdx.x;
    int orig = (t < T) ? tileSum[t] : 0;
    sh[t] = orig;
    __syncthreads();
    for (int d = 1; d < 256; d <<= 1) {
        int v = (t >= d) ? sh[t - d] : 0;
        __syncthreads();
        sh[t] += v;
        __syncthreads();
    }
    if (t < T) tileOff[t] = sh[t] - orig;
    if (t == 255) rowptr[N] = sh[255];
}

__launch_bounds__(256)
__global__ void k_tileemit(const int* __restrict__ cnt, const int* __restrict__ tileOff,
                           int* __restrict__ rowptr, int* __restrict__ cursor,
                           float* __restrict__ dis, int N) {
    __shared__ int sh[256];
    int t = threadIdx.x;
    int base = blockIdx.x * SCAN_TILE;
    int idx0 = base + t * 4;
    int v0 = 0, v1 = 0, v2 = 0, v3 = 0;
    if (idx0 + 3 < N) {
        int4 v = *(const int4*)(cnt + idx0);
        v0 = v.x; v1 = v.y; v2 = v.z; v3 = v.w;
    } else {
        if (idx0 + 0 < N) v0 = cnt[idx0 + 0];
        if (idx0 + 1 < N) v1 = cnt[idx0 + 1];
        if (idx0 + 2 < N) v2 = cnt[idx0 + 2];
        if (idx0 + 3 < N) v3 = cnt[idx0 + 3];
    }
    int s0 = v0, s1 = s0 + v1, s2 = s1 + v2, s3 = s2 + v3;
    sh[t] = s3;
    __syncthreads();
    for (int d = 1; d < 256; d <<= 1) {
        int v = (t >= d) ? sh[t - d] : 0;
        __syncthreads();
        sh[t] += v;
        __syncthreads();
    }
    int gbase = tileOff[blockIdx.x] + ((t == 0) ? 0 : sh[t - 1]);
    int ex[4] = {0, s0, s1, s2};
    int vv[4] = {v0, v1, v2, v3};
#pragma unroll
    for (int j = 0; j < 4; ++j) {
        int idx = idx0 + j;
        if (idx < N) {
            int r = gbase + ex[j];
            rowptr[idx] = r;
            cursor[idx] = r;
            dis[idx] = rsqrtf((float)vv[j] + 1.0f);
        }
    }
}

__global__ void k_scatter(const int* __restrict__ src, const int* __restrict__ dst,
                          int* __restrict__ cursor, int* __restrict__ col, int E) {
    int e = blockIdx.x * blockDim.x + threadIdx.x;
    if (e < E) {
        int pos = atomicAdd(&cursor[dst[e]], 1);
        col[pos] = src[e];
    }
}

__global__ void k_bounds(const int* __restrict__ batch, int* __restrict__ start, int N, int G) {
    int g = blockIdx.x * blockDim.x + threadIdx.x;
    if (g <= G) {
        int lo = 0, hi = N;
        while (lo < hi) { int mid = (lo + hi) >> 1; if (batch[mid] < g) lo = mid + 1; else hi = mid; }
        start[g] = lo;
    }
}

// ---------------- weight split: fp32 W[k][n] -> transposed bf16 hi/lo [n][k] ----------------

__global__ void k_cvt_w(const float* __restrict__ s0, const float* __restrict__ s1,
                        const float* __restrict__ s2, const float* __restrict__ s3,
                        const float* __restrict__ s4, const float* __restrict__ s5,
                        const float* __restrict__ s6, const float* __restrict__ s7,
                        unsigned short* __restrict__ whi, unsigned short* __restrict__ wlo) {
    int my = blockIdx.y;
    const float* src; int Ksrc, KP; size_t dstoff;
    const size_t o96 = (size_t)128 * 96, o128 = (size_t)128 * 128;
    switch (my) {
        case 0: src = s0; Ksrc = 78;  KP = 96;  dstoff = 0; break;
        case 1: src = s1; Ksrc = 78;  KP = 96;  dstoff = o96; break;
        case 2: src = s2; Ksrc = 128; KP = 128; dstoff = 2 * o96; break;
        case 3: src = s3; Ksrc = 128; KP = 128; dstoff = 2 * o96 + o128; break;
        case 4: src = s4; Ksrc = 128; KP = 128; dstoff = 2 * o96 + 2 * o128; break;
        case 5: src = s5; Ksrc = 128; KP = 128; dstoff = 2 * o96 + 3 * o128; break;
        case 6: src = s6; Ksrc = 128; KP = 128; dstoff = 2 * o96 + 4 * o128; break;
        default: src = s7; Ksrc = 128; KP = 128; dstoff = 2 * o96 + 5 * o128; break;
    }
    int i = blockIdx.x * blockDim.x + threadIdx.x;
    if (i < 128 * KP) {
        int n = i / KP, k = i - n * KP;
        float v = (k < Ksrc) ? src[(size_t)k * DIMC + n] : 0.f;
        unsigned short hi = f2b(v);
        unsigned short lo = f2b(v - b2f(hi));
        whi[dstoff + i] = hi;
        wlo[dstoff + i] = lo;
    }
}

// ---------------- pad x: fp32 [N][78] -> fp32 [N][96] (zero-padded cols) ----------------

__global__ void k_pad_x(const float* __restrict__ x, float* __restrict__ x96, int N) {
    int i = blockIdx.x * blockDim.x + threadIdx.x;
    int r = i / 24, c4 = (i - r * 24) * 4;
    if (r >= N) return;
    float v[4];
#pragma unroll
    for (int j = 0; j < 4; ++j) { int k = c4 + j; v[j] = (k < FINC) ? x[(size_t)r * FINC + k] : 0.f; }
    *(float4*)(x96 + (size_t)r * 96 + c4) = make_float4(v[0], v[1], v[2], v[3]);
}

// ---------------- fused dual-output x-GEMM (KP=96): A resident, two weight sets, bf16 t out ----------------

__launch_bounds__(256, 2)
__global__ void k_gemm_x2(const float* __restrict__ A,
                          const unsigned short* __restrict__ B0hi, const unsigned short* __restrict__ B0lo,
                          const unsigned short* __restrict__ B1hi, const unsigned short* __restrict__ B1lo,
                          const float* __restrict__ rowScale0,
                          unsigned short* __restrict__ C0, unsigned short* __restrict__ C1, int N) {
    constexpr int KP = 96, NC = 3;
    __shared__ float          ldsA[NC * 4096];   // 48 KB
    __shared__ unsigned short ldsB[2][4096];     // 16 KB
    const int tid = threadIdx.x;
    const int wave = tid >> 6, lane = tid & 63;
    const int lm = lane & 15, q = lane >> 4;
    const int wr = (wave >> 1) * 64, wc = (wave & 1) * 64;
    const int row0 = blockIdx.x * 128;

    const int au = tid & 7, ar = tid >> 3;
    const int bu = tid & 3, br = tid >> 2;

#pragma unroll
    for (int c = 0; c < NC; ++c)
#pragma unroll
        for (int p = 0; p < 4; ++p) {
            int r = p * 32 + ar;
            gld16(A + (size_t)(row0 + r) * KP + c * 32 + ((au ^ (r & 7)) << 2),
                  &ldsA[((c * 4 + p) * 256 + tid) << 2]);
        }

    const unsigned short* bh2[2] = {B0hi, B1hi};
    const unsigned short* bl2[2] = {B0lo, B1lo};

#pragma unroll
    for (int ws = 0; ws < 2; ++ws) {
        f32x4 acc[4][4];
#pragma unroll
        for (int a = 0; a < 4; ++a)
#pragma unroll
            for (int b = 0; b < 4; ++b) acc[a][b] = (f32x4){0.f, 0.f, 0.f, 0.f};

#pragma unroll
        for (int c = 0; c < NC; ++c) {
#pragma unroll
            for (int p = 0; p < 2; ++p) {
                int r = p * 64 + br;
                int so = (c << 5) + ((bu ^ ((r >> 1) & 3)) << 3);
                gld16(bh2[ws] + (size_t)r * KP + so, &ldsB[0][(p * 256 + tid) << 3]);
                gld16(bl2[ws] + (size_t)r * KP + so, &ldsB[1][(p * 256 + tid) << 3]);
            }
            asm volatile("s_waitcnt vmcnt(0)" ::: "memory");
            __builtin_amdgcn_s_barrier();
            __builtin_amdgcn_sched_barrier(0);

            short8x ah[4], al[4];
#pragma unroll
            for (int rt = 0; rt < 4; ++rt) {
                int m = wr + rt * 16 + lm;
                const float* base = &ldsA[c * 4096];
                float4 f0 = *(const float4*)&base[m * 32 + (((2 * q) ^ (m & 7)) << 2)];
                float4 f1 = *(const float4*)&base[m * 32 + ((((2 * q) + 1) ^ (m & 7)) << 2)];
                float ff[8] = {f0.x, f0.y, f0.z, f0.w, f1.x, f1.y, f1.z, f1.w};
#pragma unroll
                for (int j = 0; j < 8; ++j) {
                    unsigned short h = f2b(ff[j]);
                    ah[rt][j] = (short)h;
                    al[rt][j] = (short)f2b(ff[j] - b2f(h));
                }
            }
#pragma unroll
            for (int ct = 0; ct < 4; ++ct) {
                int n = wc + ct * 16 + lm;
                int sl = n * 32 + ((q ^ ((n >> 1) & 3)) << 3);
                short8x bh = *(const short8x*)&ldsB[0][sl];
                short8x bl = *(const short8x*)&ldsB[1][sl];
#pragma unroll
                for (int rt = 0; rt < 4; ++rt) {
                    acc[rt][ct] = __builtin_amdgcn_mfma_f32_16x16x32_bf16(bh, ah[rt], acc[rt][ct], 0, 0, 0);
                    acc[rt][ct] = __builtin_amdgcn_mfma_f32_16x16x32_bf16(bh, al[rt], acc[rt][ct], 0, 0, 0);
                    acc[rt][ct] = __builtin_amdgcn_mfma_f32_16x16x32_bf16(bl, ah[rt], acc[rt][ct], 0, 0, 0);
                }
            }
            __builtin_amdgcn_s_barrier();
        }

        unsigned short* C = ws ? C1 : C0;
#pragma unroll
        for (int rt = 0; rt < 4; ++rt) {
            int grow = row0 + wr + rt * 16 + lm;
            if (grow < N) {
                float sc = ws ? 1.f : rowScale0[grow];
#pragma unroll
                for (int ct = 0; ct < 4; ++ct) {
                    int nb = wc + ct * 16 + q * 4;
                    *(ushort4*)(C + (size_t)grow * DIMC + nb) =
                        make_ushort4(f2b(acc[rt][ct][0] * sc), f2b(acc[rt][ct][1] * sc),
                                     f2b(acc[rt][ct][2] * sc), f2b(acc[rt][ct][3] * sc));
                }
            }
        }
    }
}

// ---------------- fused dual-GEMM (KP=128): phase0 -> bf16 t, phase1 -> fp32 h + stats ----------------
// 49 KB LDS (A dbuf 32K + B single 16K + stats 1K) -> 3 blocks/CU -> grid 782 fits
// in ~1.02 block-rounds (tail-quantization fix). Per chunk: issue A(t+1), vmcnt(4)
// [A(t),B(t) landed], barrier, MFMA, barrier, issue B(t+1) (safe: all waves done).

__launch_bounds__(256, 3)
__global__ void k_gemm_d2(const float* __restrict__ A0,
                          const unsigned short* __restrict__ B0hi, const unsigned short* __restrict__ B0lo,
                          const float* __restrict__ rowScale0, unsigned short* __restrict__ C0,
                          const float* __restrict__ A1,
                          const unsigned short* __restrict__ B1hi, const unsigned short* __restrict__ B1lo,
                          const float* __restrict__ bias1, float* __restrict__ statsOut,
                          float* __restrict__ C1, int N) {
    constexpr int KP = 128, NT = 4;
    __shared__ float          ldsA[2][4096];     // 32 KB (dbuf)
    __shared__ unsigned short ldsB[2][4096];     // 16 KB (hi/lo, single chunk)
    __shared__ float sStats[256];
    const int tid = threadIdx.x;
    const int wave = tid >> 6, lane = tid & 63;
    const int lm = lane & 15, q = lane >> 4;
    const int wr = (wave >> 1) * 64, wc = (wave & 1) * 64;
    const int row0 = blockIdx.x * 128;

    const int au = tid & 7, ar = tid >> 3;
    const int bu = tid & 3, br = tid >> 2;

    const float* Aarr[2] = {A0, A1};
    const unsigned short* Bh[2] = {B0hi, B1hi};
    const unsigned short* Bl[2] = {B0lo, B1lo};

    for (int ws = 0; ws < 2; ++ws) {
        const float* A = Aarr[ws];
        const unsigned short* Bhi = Bh[ws];
        const unsigned short* Blo = Bl[ws];

        auto stageA = [&](int c, int d) {
            const int cb = c << 5;
#pragma unroll
            for (int p = 0; p < 4; ++p) {
                int r = p * 32 + ar;
                gld16(A + (size_t)(row0 + r) * KP + cb + ((au ^ (r & 7)) << 2),
                      &ldsA[d][(p * 256 + tid) << 2]);
            }
        };
        auto stageB = [&](int c) {
#pragma unroll
            for (int p = 0; p < 2; ++p) {
                int r = p * 64 + br;
                int so = (c << 5) + ((bu ^ ((r >> 1) & 3)) << 3);
                gld16(Bhi + (size_t)r * KP + so, &ldsB[0][(p * 256 + tid) << 3]);
                gld16(Blo + (size_t)r * KP + so, &ldsB[1][(p * 256 + tid) << 3]);
            }
        };

        f32x4 acc[4][4];
#pragma unroll
        for (int a = 0; a < 4; ++a)
#pragma unroll
            for (int b = 0; b < 4; ++b) acc[a][b] = (f32x4){0.f, 0.f, 0.f, 0.f};

        stageA(0, 0);
        stageB(0);
#pragma unroll
        for (int t = 0; t < NT; ++t) {
            const int cur = t & 1;
            if (t + 1 < NT) {
                stageA(t + 1, cur ^ 1);
                asm volatile("s_waitcnt vmcnt(4)" ::: "memory");
            } else {
                asm volatile("s_waitcnt vmcnt(0)" ::: "memory");
            }
            __builtin_amdgcn_s_barrier();
            __builtin_amdgcn_sched_barrier(0);

            short8x ah[4], al[4];
#pragma unroll
            for (int rt = 0; rt < 4; ++rt) {
                int m = wr + rt * 16 + lm;
                float4 f0 = *(const float4*)&ldsA[cur][m * 32 + (((2 * q) ^ (m & 7)) << 2)];
                float4 f1 = *(const float4*)&ldsA[cur][m * 32 + ((((2 * q) + 1) ^ (m & 7)) << 2)];
                float ff[8] = {f0.x, f0.y, f0.z, f0.w, f1.x, f1.y, f1.z, f1.w};
#pragma unroll
                for (int j = 0; j < 8; ++j) {
                    unsigned short h = f2b(ff[j]);
                    ah[rt][j] = (short)h;
                    al[rt][j] = (short)f2b(ff[j] - b2f(h));
                }
            }
#pragma unroll
            for (int ct = 0; ct < 4; ++ct) {
                int n = wc + ct * 16 + lm;
                int sl = n * 32 + ((q ^ ((n >> 1) & 3)) << 3);
                short8x bh = *(const short8x*)&ldsB[0][sl];
                short8x bl = *(const short8x*)&ldsB[1][sl];
#pragma unroll
                for (int rt = 0; rt < 4; ++rt) {
                    acc[rt][ct] = __builtin_amdgcn_mfma_f32_16x16x32_bf16(bh, ah[rt], acc[rt][ct], 0, 0, 0);
                    acc[rt][ct] = __builtin_amdgcn_mfma_f32_16x16x32_bf16(bh, al[rt], acc[rt][ct], 0, 0, 0);
                    acc[rt][ct] = __builtin_amdgcn_mfma_f32_16x16x32_bf16(bl, ah[rt], acc[rt][ct], 0, 0, 0);
                }
            }
            __builtin_amdgcn_s_barrier();
            if (t + 1 < NT) stageB(t + 1);
        }

        if (ws == 0) {
#pragma unroll
            for (int rt = 0; rt < 4; ++rt) {
                int grow = row0 + wr + rt * 16 + lm;
                if (grow < N) {
                    float sc = rowScale0[grow];
#pragma unroll
                    for (int ct = 0; ct < 4; ++ct) {
                        int nb = wc + ct * 16 + q * 4;
                        *(ushort4*)(C0 + (size_t)grow * DIMC + nb) =
                            make_ushort4(f2b(acc[rt][ct][0] * sc), f2b(acc[rt][ct][1] * sc),
                                         f2b(acc[rt][ct][2] * sc), f2b(acc[rt][ct][3] * sc));
                    }
                }
            }
        } else {
            float cs[4][4], cq[4][4];
#pragma unroll
            for (int a = 0; a < 4; ++a)
#pragma unroll
                for (int b = 0; b < 4; ++b) { cs[a][b] = 0.f; cq[a][b] = 0.f; }
#pragma unroll
            for (int rt = 0; rt < 4; ++rt) {
                int grow = row0 + wr + rt * 16 + lm;
                if (grow < N) {
#pragma unroll
                    for (int ct = 0; ct < 4; ++ct) {
                        int nb = wc + ct * 16 + q * 4;
                        float vv[4];
#pragma unroll
                        for (int i = 0; i < 4; ++i) {
                            float v = fmaxf(acc[rt][ct][i] + bias1[nb + i], 0.f);
                            vv[i] = v;
                            cs[ct][i] += v; cq[ct][i] = fmaf(v, v, cq[ct][i]);
                        }
                        *(float4*)(C1 + (size_t)grow * DIMC + nb) =
                            make_float4(vv[0], vv[1], vv[2], vv[3]);
                    }
                }
            }
            sStats[tid] = 0.f;
            __syncthreads();
#pragma unroll
            for (int ct = 0; ct < 4; ++ct)
#pragma unroll
                for (int i = 0; i < 4; ++i) {
                    float vs = cs[ct][i], vq = cq[ct][i];
#pragma unroll
                    for (int o = 1; o < 16; o <<= 1) { vs += __shfl_xor(vs, o); vq += __shfl_xor(vq, o); }
                    if (lm == 0) {
                        int colg = wc + ct * 16 + q * 4 + i;
                        atomicAdd(&sStats[colg], vs);
                        atomicAdd(&sStats[DIMC + colg], vq);
                    }
                }
            __syncthreads();
            atomicAdd(&statsOut[tid], sStats[tid]);
        }
    }
}

// ---------------- MFMA GEMM, 49 KB LDS / 3 blocks/CU (tail fix); BF16OUT selects t output ----------------

template<int KP, bool STATS, bool BF16OUT>
__launch_bounds__(256, 3)
__global__ void k_gemm_c(const float* __restrict__ A,
                         const unsigned short* __restrict__ Bhi,
                         const unsigned short* __restrict__ Blo,
                         const float* __restrict__ bias, const float* __restrict__ rowScale,
                         float* __restrict__ statsOut, void* __restrict__ Cv,
                         int N, int doRelu) {
    constexpr int NT = KP / 32;
    __shared__ float          ldsA[2][4096];     // 32 KB (dbuf)
    __shared__ unsigned short ldsB[2][4096];     // 16 KB (hi/lo, single chunk)
    __shared__ float sStats[256];
    const int tid = threadIdx.x;
    const int wave = tid >> 6, lane = tid & 63;
    const int lm = lane & 15, q = lane >> 4;
    const int wr = (wave >> 1) * 64, wc = (wave & 1) * 64;
    const int row0 = blockIdx.x * 128;

    const int au = tid & 7, ar = tid >> 3;
    const int bu = tid & 3, br = tid >> 2;

    auto stageA = [&](int c, int d) {
        const int cb = c << 5;
#pragma unroll
        for (int p = 0; p < 4; ++p) {
            int r = p * 32 + ar;
            gld16(A + (size_t)(row0 + r) * KP + cb + ((au ^ (r & 7)) << 2),
                  &ldsA[d][(p * 256 + tid) << 2]);
        }
    };
    auto stageB = [&](int c) {
#pragma unroll
        for (int p = 0; p < 2; ++p) {
            int r = p * 64 + br;
            int so = (c << 5) + ((bu ^ ((r >> 1) & 3)) << 3);
            gld16(Bhi + (size_t)r * KP + so, &ldsB[0][(p * 256 + tid) << 3]);
            gld16(Blo + (size_t)r * KP + so, &ldsB[1][(p * 256 + tid) << 3]);
        }
    };

    f32x4 acc[4][4];
#pragma unroll
    for (int a = 0; a < 4; ++a)
#pragma unroll
        for (int b = 0; b < 4; ++b) acc[a][b] = (f32x4){0.f, 0.f, 0.f, 0.f};

    stageA(0, 0);
    stageB(0);
#pragma unroll
    for (int t = 0; t < NT; ++t) {
        const int cur = t & 1;
        if (t + 1 < NT) {
            stageA(t + 1, cur ^ 1);
            asm volatile("s_waitcnt vmcnt(4)" ::: "memory");
        } else {
            asm volatile("s_waitcnt vmcnt(0)" ::: "memory");
        }
        __builtin_amdgcn_s_barrier();
        __builtin_amdgcn_sched_barrier(0);

        short8x ah[4], al[4];
#pragma unroll
        for (int rt = 0; rt < 4; ++rt) {
            int m = wr + rt * 16 + lm;
            float4 f0 = *(const float4*)&ldsA[cur][m * 32 + (((2 * q) ^ (m & 7)) << 2)];
            float4 f1 = *(const float4*)&ldsA[cur][m * 32 + ((((2 * q) + 1) ^ (m & 7)) << 2)];
            float ff[8] = {f0.x, f0.y, f0.z, f0.w, f1.x, f1.y, f1.z, f1.w};
#pragma unroll
            for (int j = 0; j < 8; ++j) {
                unsigned short h = f2b(ff[j]);
                ah[rt][j] = (short)h;
                al[rt][j] = (short)f2b(ff[j] - b2f(h));
            }
        }
#pragma unroll
        for (int ct = 0; ct < 4; ++ct) {
            int n = wc + ct * 16 + lm;
            int sl = n * 32 + ((q ^ ((n >> 1) & 3)) << 3);
            short8x bh = *(const short8x*)&ldsB[0][sl];
            short8x bl = *(const short8x*)&ldsB[1][sl];
#pragma unroll
            for (int rt = 0; rt < 4; ++rt) {
                acc[rt][ct] = __builtin_amdgcn_mfma_f32_16x16x32_bf16(bh, ah[rt], acc[rt][ct], 0, 0, 0);
                acc[rt][ct] = __builtin_amdgcn_mfma_f32_16x16x32_bf16(bh, al[rt], acc[rt][ct], 0, 0, 0);
                acc[rt][ct] = __builtin_amdgcn_mfma_f32_16x16x32_bf16(bl, ah[rt], acc[rt][ct], 0, 0, 0);
            }
        }
        __builtin_amdgcn_s_barrier();
        if (t + 1 < NT) stageB(t + 1);
    }

    float cs[4][4], cq[4][4];
    if constexpr (STATS) {
#pragma unroll
        for (int a = 0; a < 4; ++a)
#pragma unroll
            for (int b = 0; b < 4; ++b) { cs[a][b] = 0.f; cq[a][b] = 0.f; }
    }

#pragma unroll
    for (int rt = 0; rt < 4; ++rt) {
        int grow = row0 + wr + rt * 16 + lm;
        if (grow < N) {
            float sc = rowScale ? rowScale[grow] : 1.f;
#pragma unroll
            for (int ct = 0; ct < 4; ++ct) {
                int nb = wc + ct * 16 + q * 4;
                float vv[4];
#pragma unroll
                for (int i = 0; i < 4; ++i) {
                    float v = acc[rt][ct][i];
                    if (bias) v += bias[nb + i];
                    if (doRelu) v = fmaxf(v, 0.f);
                    v *= sc;
                    vv[i] = v;
                    if constexpr (STATS) { cs[ct][i] += v; cq[ct][i] = fmaf(v, v, cq[ct][i]); }
                }
                if constexpr (BF16OUT) {
                    *(ushort4*)((unsigned short*)Cv + (size_t)grow * DIMC + nb) =
                        make_ushort4(f2b(vv[0]), f2b(vv[1]), f2b(vv[2]), f2b(vv[3]));
                } else {
                    *(float4*)((float*)Cv + (size_t)grow * DIMC + nb) =
                        make_float4(vv[0], vv[1], vv[2], vv[3]);
                }
            }
        }
    }

    if constexpr (STATS) {
        sStats[tid] = 0.f;
        __syncthreads();
#pragma unroll
        for (int ct = 0; ct < 4; ++ct)
#pragma unroll
            for (int i = 0; i < 4; ++i) {
                float vs = cs[ct][i], vq = cq[ct][i];
#pragma unroll
                for (int o = 1; o < 16; o <<= 1) { vs += __shfl_xor(vs, o); vq += __shfl_xor(vq, o); }
                if (lm == 0) {
                    int colg = wc + ct * 16 + q * 4 + i;
                    atomicAdd(&sStats[colg], vs);
                    atomicAdd(&sStats[DIMC + colg], vq);
                }
            }
        __syncthreads();
        atomicAdd(&statsOut[tid], sStats[tid]);
    }
}

// ---------------- BN coefficients: sums -> (scale, shift) ----------------

__global__ void k_bn_coef(const float* __restrict__ bnsum, const float* __restrict__ gamma,
                          const float* __restrict__ beta, float* __restrict__ coef, float invN) {
    int c = threadIdx.x;  // 128
    float mu  = bnsum[c] * invN;
    float var = bnsum[128 + c] * invN - mu * mu;
    float inv = rsqrtf(var + 1e-5f);
    float s = gamma[c] * inv;
    coef[c] = s;
    coef[128 + c] = beta[c] - mu * s;
}

// ---- fold BN affine into next layer's W1: W'[n][k] = s[k]*w1[k][n], cvec[n] = sum_k t[k]*w1[k][n]

__global__ void k_fold_w(const float* __restrict__ w1, const float* __restrict__ coefL,
                         unsigned short* __restrict__ fwhi, unsigned short* __restrict__ fwlo,
                         float* __restrict__ cvec) {
    __shared__ float red[128];
    int n = blockIdx.x, k = threadIdx.x;
    float w = w1[(size_t)k * DIMC + n];
    float ws = w * coefL[k];
    unsigned short h = f2b(ws);
    fwhi[(size_t)n * DIMC + k] = h;
    fwlo[(size_t)n * DIMC + k] = f2b(ws - b2f(h));
    red[k] = w * coefL[DIMC + k];
    __syncthreads();
    for (int d = 64; d > 0; d >>= 1) { if (k < d) red[k] += red[k + d]; __syncthreads(); }
    if (k == 0) cvec[n] = red[0];
}

// ---------------- CSR gather aggregation (bf16 t in, fp32 out; 32 lanes/node, unroll-4 MLP) ----------------

__device__ __forceinline__ float4 ld_bf4(const unsigned short* p) {
    ushort4 u = *(const ushort4*)p;
    return make_float4(b2f(u.x), b2f(u.y), b2f(u.z), b2f(u.w));
}

// fused dual gather: blocks [0, half) do GCN (t0 -> out0, *dis + bias0, relu);
// blocks [half, 2*half) do GIN (t1 -> out1, + bias1, relu).
__global__ void k_gather2(const unsigned short* __restrict__ t0, const float* __restrict__ dis,
                          const float4* __restrict__ bias0, float4* __restrict__ out0,
                          const unsigned short* __restrict__ t1, const float4* __restrict__ bias1,
                          float4* __restrict__ out1,
                          const int* __restrict__ rowptr, const int* __restrict__ col,
                          int N, int half) {
    int b = blockIdx.x;
    bool gin = b >= half;
    int i = (gin ? b - half : b) * blockDim.x + threadIdx.x;
    int node = i >> 5, c4 = i & 31;
    if (node >= N) return;
    int s = rowptr[node], e = rowptr[node + 1];
    const unsigned short* t = gin ? t1 : t0;
    float4 acc = ld_bf4(t + (size_t)node * DIMC + c4 * 4);
    int k = s;
    for (; k + 4 <= e; k += 4) {
        int c0 = col[k], c1 = col[k + 1], c2 = col[k + 2], c3 = col[k + 3];
        float4 v0 = ld_bf4(t + (size_t)c0 * DIMC + c4 * 4);
        float4 v1 = ld_bf4(t + (size_t)c1 * DIMC + c4 * 4);
        float4 v2 = ld_bf4(t + (size_t)c2 * DIMC + c4 * 4);
        float4 v3 = ld_bf4(t + (size_t)c3 * DIMC + c4 * 4);
        acc.x += (v0.x + v1.x) + (v2.x + v3.x);
        acc.y += (v0.y + v1.y) + (v2.y + v3.y);
        acc.z += (v0.z + v1.z) + (v2.z + v3.z);
        acc.w += (v0.w + v1.w) + (v2.w + v3.w);
    }
    for (; k < e; ++k) {
        float4 v = ld_bf4(t + (size_t)col[k] * DIMC + c4 * 4);
        acc.x += v.x; acc.y += v.y; acc.z += v.z; acc.w += v.w;
    }
    float d = gin ? 1.f : dis[node];
    float4 bb = gin ? bias1[c4] : bias0[c4];
    float4 o;
    o.x = fmaxf(acc.x * d + bb.x, 0.f);
    o.y = fmaxf(acc.y * d + bb.y, 0.f);
    o.z = fmaxf(acc.z * d + bb.z, 0.f);
    o.w = fmaxf(acc.w * d + bb.w, 0.f);
    (gin ? out1 : out0)[(size_t)node * 32 + c4] = o;
}

__global__ void k_gather_gcn(const unsigned short* __restrict__ t, const int* __restrict__ rowptr,
                             const int* __restrict__ col, const float* __restrict__ dis,
                             const float4* __restrict__ bias, float4* __restrict__ out, int N) {
    int i = blockIdx.x * blockDim.x + threadIdx.x;
    int node = i >> 5, c4 = i & 31;
    if (node >= N) return;
    int s = rowptr[node], e = rowptr[node + 1];
    float4 acc = ld_bf4(t + (size_t)node * DIMC + c4 * 4);
    int k = s;
    for (; k + 4 <= e; k += 4) {
        int c0 = col[k], c1 = col[k + 1], c2 = col[k + 2], c3 = col[k + 3];
        float4 v0 = ld_bf4(t + (size_t)c0 * DIMC + c4 * 4);
        float4 v1 = ld_bf4(t + (size_t)c1 * DIMC + c4 * 4);
        float4 v2 = ld_bf4(t + (size_t)c2 * DIMC + c4 * 4);
        float4 v3 = ld_bf4(t + (size_t)c3 * DIMC + c4 * 4);
        acc.x += (v0.x + v1.x) + (v2.x + v3.x);
        acc.y += (v0.y + v1.y) + (v2.y + v3.y);
        acc.z += (v0.z + v1.z) + (v2.z + v3.z);
        acc.w += (v0.w + v1.w) + (v2.w + v3.w);
    }
    for (; k < e; ++k) {
        float4 v = ld_bf4(t + (size_t)col[k] * DIMC + c4 * 4);
        acc.x += v.x; acc.y += v.y; acc.z += v.z; acc.w += v.w;
    }
    float d = dis[node];
    float4 b = bias[c4];
    float4 o;
    o.x = fmaxf(acc.x * d + b.x, 0.f);
    o.y = fmaxf(acc.y * d + b.y, 0.f);
    o.z = fmaxf(acc.z * d + b.z, 0.f);
    o.w = fmaxf(acc.w * d + b.w, 0.f);
    out[(size_t)node * 32 + c4] = o;
}

__global__ void k_gather_gin(const unsigned short* __restrict__ t, const int* __restrict__ rowptr,
                             const int* __restrict__ col, const float4* __restrict__ bias,
                             float4* __restrict__ out, int N) {
    int i = blockIdx.x * blockDim.x + threadIdx.x;
    int node = i >> 5, c4 = i & 31;
    if (node >= N) return;
    int s = rowptr[node], e = rowptr[node + 1];
    float4 acc = ld_bf4(t + (size_t)node * DIMC + c4 * 4);
    int k = s;
    for (; k + 4 <= e; k += 4) {
        int c0 = col[k], c1 = col[k + 1], c2 = col[k + 2], c3 = col[k + 3];
        float4 v0 = ld_bf4(t + (size_t)c0 * DIMC + c4 * 4);
        float4 v1 = ld_bf4(t + (size_t)c1 * DIMC + c4 * 4);
        float4 v2 = ld_bf4(t + (size_t)c2 * DIMC + c4 * 4);
        float4 v3 = ld_bf4(t + (size_t)c3 * DIMC + c4 * 4);
        acc.x += (v0.x + v1.x) + (v2.x + v3.x);
        acc.y += (v0.y + v1.y) + (v2.y + v3.y);
        acc.z += (v0.z + v1.z) + (v2.z + v3.z);
        acc.w += (v0.w + v1.w) + (v2.w + v3.w);
    }
    for (; k < e; ++k) {
        float4 v = ld_bf4(t + (size_t)col[k] * DIMC + c4 * 4);
        acc.x += v.x; acc.y += v.y; acc.z += v.z; acc.w += v.w;
    }
    float4 b = bias[c4];
    float4 o;
    o.x = fmaxf(acc.x + b.x, 0.f);
    o.y = fmaxf(acc.y + b.y, 0.f);
    o.z = fmaxf(acc.z + b.z, 0.f);
    o.w = fmaxf(acc.w + b.w, 0.f);
    out[(size_t)node * 32 + c4] = o;
}

// ---------------- segment max (fp32) ----------------

__global__ void k_segmax_gin_all(const float* __restrict__ h0, const float* __restrict__ h1,
                                 const float* __restrict__ h2, const float* __restrict__ coef,
                                 const int* __restrict__ start, float* __restrict__ out) {
    int g = blockIdx.x, c = threadIdx.x;
    float s0 = coef[c],       t0 = coef[128 + c];
    float s1 = coef[256 + c], t1 = coef[384 + c];
    float s2 = coef[512 + c], t2 = coef[640 + c];
    int s = start[g], e = start[g + 1];
    float m0 = -INFINITY, m1 = -INFINITY, m2 = -INFINITY, mm = -INFINITY, me = -INFINITY;
    for (int n = s; n < e; ++n) {
        size_t idx = (size_t)n * DIMC + c;
        float a0 = fmaf(h0[idx], s0, t0);
        float a1 = fmaf(h1[idx], s1, t1);
        float a2 = fmaf(h2[idx], s2, t2);
        m0 = fmaxf(m0, a0); m1 = fmaxf(m1, a1); m2 = fmaxf(m2, a2);
        mm = fmaxf(mm, a0 * a1 * a2);
        me = fmaxf(me, a0 + a1 + a2);
    }
    size_t o = (size_t)g * REPW + c;
    out[o]            = m0;
    out[o + 1 * DIMC] = m1;
    out[o + 2 * DIMC] = m2;
    out[o + 3 * DIMC] = mm;
    out[o + 4 * DIMC] = me;
}

__global__ void k_segmax_gcn(const float* __restrict__ G1, const float* __restrict__ G2,
                             const int* __restrict__ start, float* __restrict__ out) {
    int g = blockIdx.x, c = threadIdx.x;
    int s = start[g], e = start[g + 1];
    float m1 = -INFINITY, m2 = -INFINITY, ma = -INFINITY, mm = -INFINITY;
    for (int n = s; n < e; ++n) {
        float a = G1[(size_t)n * DIMC + c], b = G2[(size_t)n * DIMC + c];
        m1 = fmaxf(m1, a); m2 = fmaxf(m2, b);
        ma = fmaxf(ma, a + b); mm = fmaxf(mm, a * b);
    }
    size_t o = (size_t)g * REPW + c;
    out[o + 5 * DIMC] = m1;
    out[o + 6 * DIMC] = m2;
    out[o + 7 * DIMC] = ma;
    out[o + 8 * DIMC] = mm;
}

// ---------------- launch ----------------

extern "C" void kernel_launch(void* const* d_in, const int* in_sizes, int n_in,
                              void* d_out, int out_size, void* d_ws, size_t ws_size,
                              hipStream_t stream) {
    const float* x       = (const float*)d_in[0];
    const int*   ei      = (const int*)d_in[1];
    const int*   batch   = (const int*)d_in[2];
    const float* gcn1_W  = (const float*)d_in[4];
    const float* gcn1_b  = (const float*)d_in[5];
    const float* gcn2_W  = (const float*)d_in[6];
    const float* gcn2_b  = (const float*)d_in[7];
    const float* gin0_w1 = (const float*)d_in[8];
    const float* gin0_b1 = (const float*)d_in[9];
    const float* gin0_w2 = (const float*)d_in[10];
    const float* gin0_b2 = (const float*)d_in[11];
    const float* gin_w1  = (const float*)d_in[12];
    const float* gin_b1  = (const float*)d_in[13];
    const float* gin_w2  = (const float*)d_in[14];
    const float* gin_b2  = (const float*)d_in[15];
    const float* bn_g    = (const float*)d_in[16];
    const float* bn_b    = (const float*)d_in[17];
    float* out = (float*)d_out;

    const int N = in_sizes[0] / FINC;   // 100000
    const int E = in_sizes[1] / 2;      // 400000
    const int G = out_size / REPW;      // 2500
    const int* srcv = ei;
    const int* dstv = ei + E;

    // Workspace (~263 MB, proven-safe). x96 aliases h1 (x dead before h1 written).
    // GEMM A-DMA may read up to 128 rows past N; all A-input buffers are followed
    // by other allocs -> in-bounds.
    char* ws = (char*)d_ws;
    size_t off = 0;
    auto alloc = [&](size_t bytes) { char* p = ws + off; off += (bytes + 255) & ~(size_t)255; return p; };
    int*   cnt     = (int*)alloc((size_t)N * 4);
    int*   rowptr  = (int*)alloc(((size_t)N + 1) * 4);
    int*   cursor  = (int*)alloc((size_t)N * 4);
    int*   col     = (int*)alloc((size_t)E * 4);
    float* dis     = (float*)alloc((size_t)N * 4);
    float* bnsum   = (float*)alloc(768 * 4);
    float* coef    = (float*)alloc(768 * 4);
    float* cvec    = (float*)alloc(128 * 4);
    int*   start   = (int*)alloc(((size_t)G + 1) * 4);
    int*   tileSum = (int*)alloc(256 * 4);
    int*   tileOff = (int*)alloc(256 * 4);
    const size_t o96 = (size_t)128 * 96, o128 = (size_t)128 * 128;
    const size_t wtElems = 2 * o96 + 6 * o128;
    unsigned short* whi  = (unsigned short*)alloc(wtElems * 2);
    unsigned short* wlo  = (unsigned short*)alloc(wtElems * 2);
    unsigned short* fwhi = (unsigned short*)alloc(o128 * 2);
    unsigned short* fwlo = (unsigned short*)alloc(o128 * 2);
    const size_t fbytes = (size_t)N * DIMC * 4;
    float* bufZ = (float*)alloc(fbytes);
    float* h0   = (float*)alloc(fbytes);
    float* h1   = (float*)alloc(fbytes);   // hosts x96 early
    float* h2   = (float*)alloc(fbytes);
    unsigned short* tb0 = (unsigned short*)alloc((size_t)N * DIMC * 2);
    unsigned short* tb1 = (unsigned short*)alloc((size_t)N * DIMC * 2);
    float* x96  = h1;
    (void)ws_size; (void)n_in;

    const size_t woff[8] = {0, o96, 2 * o96, 2 * o96 + o128, 2 * o96 + 2 * o128,
                            2 * o96 + 3 * o128, 2 * o96 + 4 * o128, 2 * o96 + 5 * o128};
    // order: gcn1, gin0_w1, gcn2, gin0_w2, gin_w1[0], gin_w1[1], gin_w2[0], gin_w2[1]

    const int T = 256;
    auto cdiv = [](long a, long b) { return (int)((a + b - 1) / b); };
    const int gemmGrid = cdiv(N, 128);
    const int gatherGrid = cdiv((long)N * 32, T);
    const int nTiles = cdiv(N, SCAN_TILE);
    const float invN = 1.0f / (float)N;

    // ---- CSR build + norms + graph bounds + weight split + x pad ----
    k_fill_int<<<cdiv(N, T), T, 0, stream>>>(cnt, 0, N);
    k_count<<<cdiv(E, T), T, 0, stream>>>(dstv, cnt, E);
    k_tilesum<<<nTiles, T, 0, stream>>>(cnt, tileSum, N);
    k_tilescan<<<1, T, 0, stream>>>(tileSum, tileOff, rowptr, nTiles, N);
    k_tileemit<<<nTiles, T, 0, stream>>>(cnt, tileOff, rowptr, cursor, dis, N);
    k_scatter<<<cdiv(E, T), T, 0, stream>>>(srcv, dstv, cursor, col, E);
    k_bounds<<<cdiv(G + 1, T), T, 0, stream>>>(batch, start, N, G);
    k_fill<<<3, T, 0, stream>>>(bnsum, 0.f, 768);
    {
        dim3 g(64, 8);
        k_cvt_w<<<g, T, 0, stream>>>(gcn1_W, gin0_w1, gcn2_W, gin0_w2,
                                     gin_w1, gin_w1 + o128, gin_w2, gin_w2 + o128, whi, wlo);
    }
    k_pad_x<<<cdiv((long)N * 24, T), T, 0, stream>>>(x, x96, N);

    // ---- fused x-GEMM: GCN t1 (scaled, bf16) -> tb0, GIN t0 (bf16) -> tb1 ----
    k_gemm_x2<<<gemmGrid, T, 0, stream>>>(x96, whi + woff[0], wlo + woff[0],
                                          whi + woff[1], wlo + woff[1],
                                          dis, tb0, tb1, N);

    // ---- fused gathers: g1 (tb0 -> bufZ) and z0 (tb1 -> h0) ----
    k_gather2<<<2 * gatherGrid, T, 0, stream>>>(tb0, dis,
                                                (const float4*)gcn1_b, (float4*)bufZ,
                                                tb1, (const float4*)gin0_b1,
                                                (float4*)h0, rowptr, col, N, gatherGrid);

    // ---- fused dual GEMM: t2 = g1@gcn2 (scaled, bf16) -> tb0; h0 = relu(z0@gin0_w2+b)+stats ----
    k_gemm_d2<<<gemmGrid, T, 0, stream>>>(bufZ, whi + woff[2], wlo + woff[2], dis, tb0,
                                          h0, whi + woff[3], wlo + woff[3], gin0_b2,
                                          bnsum, h0, N);

    // ---- GCN tail ----
    k_gather_gcn<<<gatherGrid, T, 0, stream>>>(tb0, rowptr, col, dis,
                                               (const float4*)gcn2_b, (float4*)h2, N);     // g2 -> h2
    k_segmax_gcn<<<G, DIMC, 0, stream>>>(bufZ, h2, start, out);                            // groups 5..8

    // ---- GIN layer 1 prep ----
    k_bn_coef<<<1, DIMC, 0, stream>>>(bnsum, bn_g, bn_b, coef, invN);
    k_fold_w<<<DIMC, DIMC, 0, stream>>>(gin_w1, coef, fwhi, fwlo, cvec);

    // ---- GIN layer 1 (x96 in h1 dead from here) ----
    k_gemm_c<128, false, true><<<gemmGrid, T, 0, stream>>>(h0, fwhi, fwlo,
                                                           cvec, nullptr, nullptr, tb0, N, 0);
    k_gather_gin<<<gatherGrid, T, 0, stream>>>(tb0, rowptr, col,
                                               (const float4*)gin_b1, (float4*)bufZ, N);
    k_gemm_c<128, true, false><<<gemmGrid, T, 0, stream>>>(bufZ, whi + woff[6], wlo + woff[6],
                                                           gin_b2, nullptr, bnsum + 256, h1, N, 1);
    k_bn_coef<<<1, DIMC, 0, stream>>>(bnsum + 256, bn_g + DIMC, bn_b + DIMC, coef + 256, invN);
    k_fold_w<<<DIMC, DIMC, 0, stream>>>(gin_w1 + o128, coef + 256, fwhi, fwlo, cvec);

    // ---- GIN layer 2 (h2's g2 role ended at segmax; becomes final h2 plane) ----
    k_gemm_c<128, false, true><<<gemmGrid, T, 0, stream>>>(h1, fwhi, fwlo,
                                                           cvec, nullptr, nullptr, tb0, N, 0);
    k_gather_gin<<<gatherGrid, T, 0, stream>>>(tb0, rowptr, col,
                                               (const float4*)(gin_b1 + DIMC), (float4*)bufZ, N);
    k_gemm_c<128, true, false><<<gemmGrid, T, 0, stream>>>(bufZ, whi + woff[7], wlo + woff[7],
                                                           gin_b2 + DIMC, nullptr, bnsum + 512, h2, N, 1);
    k_bn_coef<<<1, DIMC, 0, stream>>>(bnsum + 512, bn_g + 2 * DIMC, bn_b + 2 * DIMC, coef + 512, invN);

    k_segmax_gin_all<<<G, DIMC, 0, stream>>>(h0, h1, h2, coef, start, out);                // groups 0..4
}

// Round 19
// 666.410 us; speedup vs baseline: 1.0670x; 1.0670x over previous
//
#include <hip/hip_runtime.h>
#include <math.h>

#define DIMC 128
#define FINC 78
#define REPW 1152        // 9 * 128
#define SCAN_TILE 1024   // elements per scan tile (256 threads x 4)

typedef __attribute__((ext_vector_type(8))) short short8x;
typedef __attribute__((ext_vector_type(4))) float f32x4;
typedef unsigned int u32;
typedef const __attribute__((address_space(1))) u32* gas_u32p;
typedef __attribute__((address_space(3))) u32* las_u32p;

__device__ inline float b2f(unsigned short u) {
    union { unsigned int i; float f; } v; v.i = ((unsigned int)u) << 16; return v.f;
}
__device__ inline unsigned short f2b(float f) {
    union { float f; unsigned int i; } v; v.f = f;
    unsigned int r = (v.i + 0x7FFFu + ((v.i >> 16) & 1u)) >> 16;
    return (unsigned short)r;
}

// 16B global -> LDS DMA (LDS dest = wave-uniform base + lane*16; our dest is linear in tid).
__device__ __forceinline__ void gld16(const void* g, void* l) {
    __builtin_amdgcn_global_load_lds((gas_u32p)g, (las_u32p)l, 16, 0, 0);
}

// ---------------- setup kernels ----------------

__global__ void k_fill_int(int* __restrict__ p, int v, int n) {
    int i = blockIdx.x * blockDim.x + threadIdx.x;
    if (i < n) p[i] = v;
}

__global__ void k_fill(float* __restrict__ p, float v, int n) {
    int i = blockIdx.x * blockDim.x + threadIdx.x;
    if (i < n) p[i] = v;
}

__global__ void k_count(const int* __restrict__ dst, int* __restrict__ cnt, int E) {
    int e = blockIdx.x * blockDim.x + threadIdx.x;
    if (e < E) atomicAdd(&cnt[dst[e]], 1);
}

__launch_bounds__(256)
__global__ void k_tilesum(const int* __restrict__ cnt, int* __restrict__ tileSum, int N) {
    __shared__ int red[256];
    int base = blockIdx.x * SCAN_TILE;
    int s = 0;
    for (int i = threadIdx.x; i < SCAN_TILE; i += 256) {
        int idx = base + i;
        if (idx < N) s += cnt[idx];
    }
    red[threadIdx.x] = s;
    __syncthreads();
    for (int d = 128; d > 0; d >>= 1) {
        if (threadIdx.x < d) red[threadIdx.x] += red[threadIdx.x + d];
        __syncthreads();
    }
    if (threadIdx.x == 0) tileSum[blockIdx.x] = red[0];
}

__launch_bounds__(256)
__global__ void k_tilescan(const int* __restrict__ tileSum, int* __restrict__ tileOff,
                           int* __restrict__ rowptr, int T, int N) {
    __shared__ int sh[256];
    int t = threadIdx.x;
    int orig = (t < T) ? tileSum[t] : 0;
    sh[t] = orig;
    __syncthreads();
    for (int d = 1; d < 256; d <<= 1) {
        int v = (t >= d) ? sh[t - d] : 0;
        __syncthreads();
        sh[t] += v;
        __syncthreads();
    }
    if (t < T) tileOff[t] = sh[t] - orig;
    if (t == 255) rowptr[N] = sh[255];
}

__launch_bounds__(256)
__global__ void k_tileemit(const int* __restrict__ cnt, const int* __restrict__ tileOff,
                           int* __restrict__ rowptr, int* __restrict__ cursor,
                           float* __restrict__ dis, int N) {
    __shared__ int sh[256];
    int t = threadIdx.x;
    int base = blockIdx.x * SCAN_TILE;
    int idx0 = base + t * 4;
    int v0 = 0, v1 = 0, v2 = 0, v3 = 0;
    if (idx0 + 3 < N) {
        int4 v = *(const int4*)(cnt + idx0);
        v0 = v.x; v1 = v.y; v2 = v.z; v3 = v.w;
    } else {
        if (idx0 + 0 < N) v0 = cnt[idx0 + 0];
        if (idx0 + 1 < N) v1 = cnt[idx0 + 1];
        if (idx0 + 2 < N) v2 = cnt[idx0 + 2];
        if (idx0 + 3 < N) v3 = cnt[idx0 + 3];
    }
    int s0 = v0, s1 = s0 + v1, s2 = s1 + v2, s3 = s2 + v3;
    sh[t] = s3;
    __syncthreads();
    for (int d = 1; d < 256; d <<= 1) {
        int v = (t >= d) ? sh[t - d] : 0;
        __syncthreads();
        sh[t] += v;
        __syncthreads();
    }
    int gbase = tileOff[blockIdx.x] + ((t == 0) ? 0 : sh[t - 1]);
    int ex[4] = {0, s0, s1, s2};
    int vv[4] = {v0, v1, v2, v3};
#pragma unroll
    for (int j = 0; j < 4; ++j) {
        int idx = idx0 + j;
        if (idx < N) {
            int r = gbase + ex[j];
            rowptr[idx] = r;
            cursor[idx] = r;
            dis[idx] = rsqrtf((float)vv[j] + 1.0f);
        }
    }
}

__global__ void k_scatter(const int* __restrict__ src, const int* __restrict__ dst,
                          int* __restrict__ cursor, int* __restrict__ col, int E) {
    int e = blockIdx.x * blockDim.x + threadIdx.x;
    if (e < E) {
        int pos = atomicAdd(&cursor[dst[e]], 1);
        col[pos] = src[e];
    }
}

__global__ void k_bounds(const int* __restrict__ batch, int* __restrict__ start, int N, int G) {
    int g = blockIdx.x * blockDim.x + threadIdx.x;
    if (g <= G) {
        int lo = 0, hi = N;
        while (lo < hi) { int mid = (lo + hi) >> 1; if (batch[mid] < g) lo = mid + 1; else hi = mid; }
        start[g] = lo;
    }
}

// ---------------- weight split: fp32 W[k][n] -> transposed bf16 hi/lo [n][k] ----------------

__global__ void k_cvt_w(const float* __restrict__ s0, const float* __restrict__ s1,
                        const float* __restrict__ s2, const float* __restrict__ s3,
                        const float* __restrict__ s4, const float* __restrict__ s5,
                        const float* __restrict__ s6, const float* __restrict__ s7,
                        unsigned short* __restrict__ whi, unsigned short* __restrict__ wlo) {
    int my = blockIdx.y;
    const float* src; int Ksrc, KP; size_t dstoff;
    const size_t o96 = (size_t)128 * 96, o128 = (size_t)128 * 128;
    switch (my) {
        case 0: src = s0; Ksrc = 78;  KP = 96;  dstoff = 0; break;
        case 1: src = s1; Ksrc = 78;  KP = 96;  dstoff = o96; break;
        case 2: src = s2; Ksrc = 128; KP = 128; dstoff = 2 * o96; break;
        case 3: src = s3; Ksrc = 128; KP = 128; dstoff = 2 * o96 + o128; break;
        case 4: src = s4; Ksrc = 128; KP = 128; dstoff = 2 * o96 + 2 * o128; break;
        case 5: src = s5; Ksrc = 128; KP = 128; dstoff = 2 * o96 + 3 * o128; break;
        case 6: src = s6; Ksrc = 128; KP = 128; dstoff = 2 * o96 + 4 * o128; break;
        default: src = s7; Ksrc = 128; KP = 128; dstoff = 2 * o96 + 5 * o128; break;
    }
    int i = blockIdx.x * blockDim.x + threadIdx.x;
    if (i < 128 * KP) {
        int n = i / KP, k = i - n * KP;
        float v = (k < Ksrc) ? src[(size_t)k * DIMC + n] : 0.f;
        unsigned short hi = f2b(v);
        unsigned short lo = f2b(v - b2f(hi));
        whi[dstoff + i] = hi;
        wlo[dstoff + i] = lo;
    }
}

// ---------------- pad x: fp32 [N][78] -> fp32 [N][96] (zero-padded cols) ----------------

__global__ void k_pad_x(const float* __restrict__ x, float* __restrict__ x96, int N) {
    int i = blockIdx.x * blockDim.x + threadIdx.x;
    int r = i / 24, c4 = (i - r * 24) * 4;
    if (r >= N) return;
    float v[4];
#pragma unroll
    for (int j = 0; j < 4; ++j) { int k = c4 + j; v[j] = (k < FINC) ? x[(size_t)r * FINC + k] : 0.f; }
    *(float4*)(x96 + (size_t)r * 96 + c4) = make_float4(v[0], v[1], v[2], v[3]);
}

// ---------------- fused dual-output x-GEMM (KP=96): A resident, two weight sets, bf16 t out ----------------

__launch_bounds__(256, 2)
__global__ void k_gemm_x2(const float* __restrict__ A,
                          const unsigned short* __restrict__ B0hi, const unsigned short* __restrict__ B0lo,
                          const unsigned short* __restrict__ B1hi, const unsigned short* __restrict__ B1lo,
                          const float* __restrict__ rowScale0,
                          unsigned short* __restrict__ C0, unsigned short* __restrict__ C1, int N) {
    constexpr int KP = 96, NC = 3;
    __shared__ float          ldsA[NC * 4096];   // 48 KB
    __shared__ unsigned short ldsB[2][4096];     // 16 KB
    const int tid = threadIdx.x;
    const int wave = tid >> 6, lane = tid & 63;
    const int lm = lane & 15, q = lane >> 4;
    const int wr = (wave >> 1) * 64, wc = (wave & 1) * 64;
    const int row0 = blockIdx.x * 128;

    const int au = tid & 7, ar = tid >> 3;
    const int bu = tid & 3, br = tid >> 2;

#pragma unroll
    for (int c = 0; c < NC; ++c)
#pragma unroll
        for (int p = 0; p < 4; ++p) {
            int r = p * 32 + ar;
            gld16(A + (size_t)(row0 + r) * KP + c * 32 + ((au ^ (r & 7)) << 2),
                  &ldsA[((c * 4 + p) * 256 + tid) << 2]);
        }

    const unsigned short* bh2[2] = {B0hi, B1hi};
    const unsigned short* bl2[2] = {B0lo, B1lo};

#pragma unroll
    for (int ws = 0; ws < 2; ++ws) {
        f32x4 acc[4][4];
#pragma unroll
        for (int a = 0; a < 4; ++a)
#pragma unroll
            for (int b = 0; b < 4; ++b) acc[a][b] = (f32x4){0.f, 0.f, 0.f, 0.f};

#pragma unroll
        for (int c = 0; c < NC; ++c) {
#pragma unroll
            for (int p = 0; p < 2; ++p) {
                int r = p * 64 + br;
                int so = (c << 5) + ((bu ^ ((r >> 1) & 3)) << 3);
                gld16(bh2[ws] + (size_t)r * KP + so, &ldsB[0][(p * 256 + tid) << 3]);
                gld16(bl2[ws] + (size_t)r * KP + so, &ldsB[1][(p * 256 + tid) << 3]);
            }
            asm volatile("s_waitcnt vmcnt(0)" ::: "memory");
            __builtin_amdgcn_s_barrier();
            __builtin_amdgcn_sched_barrier(0);

            short8x ah[4], al[4];
#pragma unroll
            for (int rt = 0; rt < 4; ++rt) {
                int m = wr + rt * 16 + lm;
                const float* base = &ldsA[c * 4096];
                float4 f0 = *(const float4*)&base[m * 32 + (((2 * q) ^ (m & 7)) << 2)];
                float4 f1 = *(const float4*)&base[m * 32 + ((((2 * q) + 1) ^ (m & 7)) << 2)];
                float ff[8] = {f0.x, f0.y, f0.z, f0.w, f1.x, f1.y, f1.z, f1.w};
#pragma unroll
                for (int j = 0; j < 8; ++j) {
                    unsigned short h = f2b(ff[j]);
                    ah[rt][j] = (short)h;
                    al[rt][j] = (short)f2b(ff[j] - b2f(h));
                }
            }
#pragma unroll
            for (int ct = 0; ct < 4; ++ct) {
                int n = wc + ct * 16 + lm;
                int sl = n * 32 + ((q ^ ((n >> 1) & 3)) << 3);
                short8x bh = *(const short8x*)&ldsB[0][sl];
                short8x bl = *(const short8x*)&ldsB[1][sl];
#pragma unroll
                for (int rt = 0; rt < 4; ++rt) {
                    acc[rt][ct] = __builtin_amdgcn_mfma_f32_16x16x32_bf16(bh, ah[rt], acc[rt][ct], 0, 0, 0);
                    acc[rt][ct] = __builtin_amdgcn_mfma_f32_16x16x32_bf16(bh, al[rt], acc[rt][ct], 0, 0, 0);
                    acc[rt][ct] = __builtin_amdgcn_mfma_f32_16x16x32_bf16(bl, ah[rt], acc[rt][ct], 0, 0, 0);
                }
            }
            __builtin_amdgcn_s_barrier();
        }

        unsigned short* C = ws ? C1 : C0;
#pragma unroll
        for (int rt = 0; rt < 4; ++rt) {
            int grow = row0 + wr + rt * 16 + lm;
            if (grow < N) {
                float sc = ws ? 1.f : rowScale0[grow];
#pragma unroll
                for (int ct = 0; ct < 4; ++ct) {
                    int nb = wc + ct * 16 + q * 4;
                    *(ushort4*)(C + (size_t)grow * DIMC + nb) =
                        make_ushort4(f2b(acc[rt][ct][0] * sc), f2b(acc[rt][ct][1] * sc),
                                     f2b(acc[rt][ct][2] * sc), f2b(acc[rt][ct][3] * sc));
                }
            }
        }
    }
}

// ---------------- fused dual-GEMM (KP=128): phase0 -> bf16 t, phase1 -> fp32 h + stats ----------------

__launch_bounds__(256, 2)
__global__ void k_gemm_d2(const float* __restrict__ A0,
                          const unsigned short* __restrict__ B0hi, const unsigned short* __restrict__ B0lo,
                          const float* __restrict__ rowScale0, unsigned short* __restrict__ C0,
                          const float* __restrict__ A1,
                          const unsigned short* __restrict__ B1hi, const unsigned short* __restrict__ B1lo,
                          const float* __restrict__ bias1, float* __restrict__ statsOut,
                          float* __restrict__ C1, int N) {
    constexpr int KP = 128, NT = 4;
    __shared__ float          ldsA[2][4096];
    __shared__ unsigned short ldsB[2][2][4096];
    __shared__ float sStats[256];
    const int tid = threadIdx.x;
    const int wave = tid >> 6, lane = tid & 63;
    const int lm = lane & 15, q = lane >> 4;
    const int wr = (wave >> 1) * 64, wc = (wave & 1) * 64;
    const int row0 = blockIdx.x * 128;

    const int au = tid & 7, ar = tid >> 3;
    const int bu = tid & 3, br = tid >> 2;

    const float* Aarr[2] = {A0, A1};
    const unsigned short* Bh[2] = {B0hi, B1hi};
    const unsigned short* Bl[2] = {B0lo, B1lo};

    for (int ws = 0; ws < 2; ++ws) {
        const float* A = Aarr[ws];
        const unsigned short* Bhi = Bh[ws];
        const unsigned short* Blo = Bl[ws];

        auto stage = [&](int c, int d) {
            const int cb = c << 5;
#pragma unroll
            for (int p = 0; p < 4; ++p) {
                int r = p * 32 + ar;
                gld16(A + (size_t)(row0 + r) * KP + cb + ((au ^ (r & 7)) << 2),
                      &ldsA[d][(p * 256 + tid) << 2]);
            }
#pragma unroll
            for (int p = 0; p < 2; ++p) {
                int r = p * 64 + br;
                int so = cb + ((bu ^ ((r >> 1) & 3)) << 3);
                gld16(Bhi + (size_t)r * KP + so, &ldsB[d][0][(p * 256 + tid) << 3]);
                gld16(Blo + (size_t)r * KP + so, &ldsB[d][1][(p * 256 + tid) << 3]);
            }
        };

        f32x4 acc[4][4];
#pragma unroll
        for (int a = 0; a < 4; ++a)
#pragma unroll
            for (int b = 0; b < 4; ++b) acc[a][b] = (f32x4){0.f, 0.f, 0.f, 0.f};

        stage(0, 0);
#pragma unroll
        for (int t = 0; t < NT; ++t) {
            const int cur = t & 1;
            if (t + 1 < NT) {
                stage(t + 1, cur ^ 1);
                asm volatile("s_waitcnt vmcnt(8)" ::: "memory");
            } else {
                asm volatile("s_waitcnt vmcnt(0)" ::: "memory");
            }
            __builtin_amdgcn_s_barrier();
            __builtin_amdgcn_sched_barrier(0);

            short8x ah[4], al[4];
#pragma unroll
            for (int rt = 0; rt < 4; ++rt) {
                int m = wr + rt * 16 + lm;
                float4 f0 = *(const float4*)&ldsA[cur][m * 32 + (((2 * q) ^ (m & 7)) << 2)];
                float4 f1 = *(const float4*)&ldsA[cur][m * 32 + ((((2 * q) + 1) ^ (m & 7)) << 2)];
                float ff[8] = {f0.x, f0.y, f0.z, f0.w, f1.x, f1.y, f1.z, f1.w};
#pragma unroll
                for (int j = 0; j < 8; ++j) {
                    unsigned short h = f2b(ff[j]);
                    ah[rt][j] = (short)h;
                    al[rt][j] = (short)f2b(ff[j] - b2f(h));
                }
            }
#pragma unroll
            for (int ct = 0; ct < 4; ++ct) {
                int n = wc + ct * 16 + lm;
                int sl = n * 32 + ((q ^ ((n >> 1) & 3)) << 3);
                short8x bh = *(const short8x*)&ldsB[cur][0][sl];
                short8x bl = *(const short8x*)&ldsB[cur][1][sl];
#pragma unroll
                for (int rt = 0; rt < 4; ++rt) {
                    acc[rt][ct] = __builtin_amdgcn_mfma_f32_16x16x32_bf16(bh, ah[rt], acc[rt][ct], 0, 0, 0);
                    acc[rt][ct] = __builtin_amdgcn_mfma_f32_16x16x32_bf16(bh, al[rt], acc[rt][ct], 0, 0, 0);
                    acc[rt][ct] = __builtin_amdgcn_mfma_f32_16x16x32_bf16(bl, ah[rt], acc[rt][ct], 0, 0, 0);
                }
            }
            __builtin_amdgcn_s_barrier();
        }

        if (ws == 0) {
#pragma unroll
            for (int rt = 0; rt < 4; ++rt) {
                int grow = row0 + wr + rt * 16 + lm;
                if (grow < N) {
                    float sc = rowScale0[grow];
#pragma unroll
                    for (int ct = 0; ct < 4; ++ct) {
                        int nb = wc + ct * 16 + q * 4;
                        *(ushort4*)(C0 + (size_t)grow * DIMC + nb) =
                            make_ushort4(f2b(acc[rt][ct][0] * sc), f2b(acc[rt][ct][1] * sc),
                                         f2b(acc[rt][ct][2] * sc), f2b(acc[rt][ct][3] * sc));
                    }
                }
            }
        } else {
            float cs[4][4], cq[4][4];
#pragma unroll
            for (int a = 0; a < 4; ++a)
#pragma unroll
                for (int b = 0; b < 4; ++b) { cs[a][b] = 0.f; cq[a][b] = 0.f; }
#pragma unroll
            for (int rt = 0; rt < 4; ++rt) {
                int grow = row0 + wr + rt * 16 + lm;
                if (grow < N) {
#pragma unroll
                    for (int ct = 0; ct < 4; ++ct) {
                        int nb = wc + ct * 16 + q * 4;
                        float vv[4];
#pragma unroll
                        for (int i = 0; i < 4; ++i) {
                            float v = fmaxf(acc[rt][ct][i] + bias1[nb + i], 0.f);
                            vv[i] = v;
                            cs[ct][i] += v; cq[ct][i] = fmaf(v, v, cq[ct][i]);
                        }
                        *(float4*)(C1 + (size_t)grow * DIMC + nb) =
                            make_float4(vv[0], vv[1], vv[2], vv[3]);
                    }
                }
            }
            sStats[tid] = 0.f;
            __syncthreads();
#pragma unroll
            for (int ct = 0; ct < 4; ++ct)
#pragma unroll
                for (int i = 0; i < 4; ++i) {
                    float vs = cs[ct][i], vq = cq[ct][i];
#pragma unroll
                    for (int o = 1; o < 16; o <<= 1) { vs += __shfl_xor(vs, o); vq += __shfl_xor(vq, o); }
                    if (lm == 0) {
                        int colg = wc + ct * 16 + q * 4 + i;
                        atomicAdd(&sStats[colg], vs);
                        atomicAdd(&sStats[DIMC + colg], vq);
                    }
                }
            __syncthreads();
            atomicAdd(&statsOut[tid], sStats[tid]);
        }
    }
}

// ---------------- MFMA GEMM, COALESCED DMA staging; BF16OUT selects t-plane output ----------------

template<int KP, bool STATS, bool BF16OUT>
__launch_bounds__(256, 2)
__global__ void k_gemm_c(const float* __restrict__ A,
                         const unsigned short* __restrict__ Bhi,
                         const unsigned short* __restrict__ Blo,
                         const float* __restrict__ bias, const float* __restrict__ rowScale,
                         float* __restrict__ statsOut, void* __restrict__ Cv,
                         int N, int doRelu) {
    constexpr int NT = KP / 32;
    __shared__ float          ldsA[2][4096];
    __shared__ unsigned short ldsB[2][2][4096];
    __shared__ float sStats[256];
    const int tid = threadIdx.x;
    const int wave = tid >> 6, lane = tid & 63;
    const int lm = lane & 15, q = lane >> 4;
    const int wr = (wave >> 1) * 64, wc = (wave & 1) * 64;
    const int row0 = blockIdx.x * 128;

    const int au = tid & 7, ar = tid >> 3;
    const int bu = tid & 3, br = tid >> 2;

    auto stage = [&](int c, int d) {
        const int cb = c << 5;
#pragma unroll
        for (int p = 0; p < 4; ++p) {
            int r = p * 32 + ar;
            gld16(A + (size_t)(row0 + r) * KP + cb + ((au ^ (r & 7)) << 2),
                  &ldsA[d][(p * 256 + tid) << 2]);
        }
#pragma unroll
        for (int p = 0; p < 2; ++p) {
            int r = p * 64 + br;
            int so = cb + ((bu ^ ((r >> 1) & 3)) << 3);
            gld16(Bhi + (size_t)r * KP + so, &ldsB[d][0][(p * 256 + tid) << 3]);
            gld16(Blo + (size_t)r * KP + so, &ldsB[d][1][(p * 256 + tid) << 3]);
        }
    };

    f32x4 acc[4][4];
#pragma unroll
    for (int a = 0; a < 4; ++a)
#pragma unroll
        for (int b = 0; b < 4; ++b) acc[a][b] = (f32x4){0.f, 0.f, 0.f, 0.f};

    stage(0, 0);
#pragma unroll
    for (int t = 0; t < NT; ++t) {
        const int cur = t & 1;
        if (t + 1 < NT) {
            stage(t + 1, cur ^ 1);
            asm volatile("s_waitcnt vmcnt(8)" ::: "memory");
        } else {
            asm volatile("s_waitcnt vmcnt(0)" ::: "memory");
        }
        __builtin_amdgcn_s_barrier();
        __builtin_amdgcn_sched_barrier(0);

        short8x ah[4], al[4];
#pragma unroll
        for (int rt = 0; rt < 4; ++rt) {
            int m = wr + rt * 16 + lm;
            float4 f0 = *(const float4*)&ldsA[cur][m * 32 + (((2 * q) ^ (m & 7)) << 2)];
            float4 f1 = *(const float4*)&ldsA[cur][m * 32 + ((((2 * q) + 1) ^ (m & 7)) << 2)];
            float ff[8] = {f0.x, f0.y, f0.z, f0.w, f1.x, f1.y, f1.z, f1.w};
#pragma unroll
            for (int j = 0; j < 8; ++j) {
                unsigned short h = f2b(ff[j]);
                ah[rt][j] = (short)h;
                al[rt][j] = (short)f2b(ff[j] - b2f(h));
            }
        }
#pragma unroll
        for (int ct = 0; ct < 4; ++ct) {
            int n = wc + ct * 16 + lm;
            int sl = n * 32 + ((q ^ ((n >> 1) & 3)) << 3);
            short8x bh = *(const short8x*)&ldsB[cur][0][sl];
            short8x bl = *(const short8x*)&ldsB[cur][1][sl];
#pragma unroll
            for (int rt = 0; rt < 4; ++rt) {
                acc[rt][ct] = __builtin_amdgcn_mfma_f32_16x16x32_bf16(bh, ah[rt], acc[rt][ct], 0, 0, 0);
                acc[rt][ct] = __builtin_amdgcn_mfma_f32_16x16x32_bf16(bh, al[rt], acc[rt][ct], 0, 0, 0);
                acc[rt][ct] = __builtin_amdgcn_mfma_f32_16x16x32_bf16(bl, ah[rt], acc[rt][ct], 0, 0, 0);
            }
        }
        __builtin_amdgcn_s_barrier();
    }

    float cs[4][4], cq[4][4];
    if constexpr (STATS) {
#pragma unroll
        for (int a = 0; a < 4; ++a)
#pragma unroll
            for (int b = 0; b < 4; ++b) { cs[a][b] = 0.f; cq[a][b] = 0.f; }
    }

#pragma unroll
    for (int rt = 0; rt < 4; ++rt) {
        int grow = row0 + wr + rt * 16 + lm;
        if (grow < N) {
            float sc = rowScale ? rowScale[grow] : 1.f;
#pragma unroll
            for (int ct = 0; ct < 4; ++ct) {
                int nb = wc + ct * 16 + q * 4;
                float vv[4];
#pragma unroll
                for (int i = 0; i < 4; ++i) {
                    float v = acc[rt][ct][i];
                    if (bias) v += bias[nb + i];
                    if (doRelu) v = fmaxf(v, 0.f);
                    v *= sc;
                    vv[i] = v;
                    if constexpr (STATS) { cs[ct][i] += v; cq[ct][i] = fmaf(v, v, cq[ct][i]); }
                }
                if constexpr (BF16OUT) {
                    *(ushort4*)((unsigned short*)Cv + (size_t)grow * DIMC + nb) =
                        make_ushort4(f2b(vv[0]), f2b(vv[1]), f2b(vv[2]), f2b(vv[3]));
                } else {
                    *(float4*)((float*)Cv + (size_t)grow * DIMC + nb) =
                        make_float4(vv[0], vv[1], vv[2], vv[3]);
                }
            }
        }
    }

    if constexpr (STATS) {
        sStats[tid] = 0.f;
        __syncthreads();
#pragma unroll
        for (int ct = 0; ct < 4; ++ct)
#pragma unroll
            for (int i = 0; i < 4; ++i) {
                float vs = cs[ct][i], vq = cq[ct][i];
#pragma unroll
                for (int o = 1; o < 16; o <<= 1) { vs += __shfl_xor(vs, o); vq += __shfl_xor(vq, o); }
                if (lm == 0) {
                    int colg = wc + ct * 16 + q * 4 + i;
                    atomicAdd(&sStats[colg], vs);
                    atomicAdd(&sStats[DIMC + colg], vq);
                }
            }
        __syncthreads();
        atomicAdd(&statsOut[tid], sStats[tid]);
    }
}

// ---------------- BN coefficients: sums -> (scale, shift) ----------------

__global__ void k_bn_coef(const float* __restrict__ bnsum, const float* __restrict__ gamma,
                          const float* __restrict__ beta, float* __restrict__ coef, float invN) {
    int c = threadIdx.x;  // 128
    float mu  = bnsum[c] * invN;
    float var = bnsum[128 + c] * invN - mu * mu;
    float inv = rsqrtf(var + 1e-5f);
    float s = gamma[c] * inv;
    coef[c] = s;
    coef[128 + c] = beta[c] - mu * s;
}

// ---- fold BN affine into next layer's W1: W'[n][k] = s[k]*w1[k][n], cvec[n] = sum_k t[k]*w1[k][n]

__global__ void k_fold_w(const float* __restrict__ w1, const float* __restrict__ coefL,
                         unsigned short* __restrict__ fwhi, unsigned short* __restrict__ fwlo,
                         float* __restrict__ cvec) {
    __shared__ float red[128];
    int n = blockIdx.x, k = threadIdx.x;
    float w = w1[(size_t)k * DIMC + n];
    float ws = w * coefL[k];
    unsigned short h = f2b(ws);
    fwhi[(size_t)n * DIMC + k] = h;
    fwlo[(size_t)n * DIMC + k] = f2b(ws - b2f(h));
    red[k] = w * coefL[DIMC + k];
    __syncthreads();
    for (int d = 64; d > 0; d >>= 1) { if (k < d) red[k] += red[k + d]; __syncthreads(); }
    if (k == 0) cvec[n] = red[0];
}

// ---------------- CSR gather aggregation (bf16 t in, fp32 out; 32 lanes/node, unroll-4 MLP) ----------------

__device__ __forceinline__ float4 ld_bf4(const unsigned short* p) {
    ushort4 u = *(const ushort4*)p;
    return make_float4(b2f(u.x), b2f(u.y), b2f(u.z), b2f(u.w));
}

// fused dual gather: blocks [0, half) do GCN (t0 -> out0, *dis + bias0, relu);
// blocks [half, 2*half) do GIN (t1 -> out1, + bias1, relu).
__global__ void k_gather2(const unsigned short* __restrict__ t0, const float* __restrict__ dis,
                          const float4* __restrict__ bias0, float4* __restrict__ out0,
                          const unsigned short* __restrict__ t1, const float4* __restrict__ bias1,
                          float4* __restrict__ out1,
                          const int* __restrict__ rowptr, const int* __restrict__ col,
                          int N, int half) {
    int b = blockIdx.x;
    bool gin = b >= half;
    int i = (gin ? b - half : b) * blockDim.x + threadIdx.x;
    int node = i >> 5, c4 = i & 31;
    if (node >= N) return;
    int s = rowptr[node], e = rowptr[node + 1];
    const unsigned short* t = gin ? t1 : t0;
    float4 acc = ld_bf4(t + (size_t)node * DIMC + c4 * 4);
    int k = s;
    for (; k + 4 <= e; k += 4) {
        int c0 = col[k], c1 = col[k + 1], c2 = col[k + 2], c3 = col[k + 3];
        float4 v0 = ld_bf4(t + (size_t)c0 * DIMC + c4 * 4);
        float4 v1 = ld_bf4(t + (size_t)c1 * DIMC + c4 * 4);
        float4 v2 = ld_bf4(t + (size_t)c2 * DIMC + c4 * 4);
        float4 v3 = ld_bf4(t + (size_t)c3 * DIMC + c4 * 4);
        acc.x += (v0.x + v1.x) + (v2.x + v3.x);
        acc.y += (v0.y + v1.y) + (v2.y + v3.y);
        acc.z += (v0.z + v1.z) + (v2.z + v3.z);
        acc.w += (v0.w + v1.w) + (v2.w + v3.w);
    }
    for (; k < e; ++k) {
        float4 v = ld_bf4(t + (size_t)col[k] * DIMC + c4 * 4);
        acc.x += v.x; acc.y += v.y; acc.z += v.z; acc.w += v.w;
    }
    float d = gin ? 1.f : dis[node];
    float4 bb = gin ? bias1[c4] : bias0[c4];
    float4 o;
    o.x = fmaxf(acc.x * d + bb.x, 0.f);
    o.y = fmaxf(acc.y * d + bb.y, 0.f);
    o.z = fmaxf(acc.z * d + bb.z, 0.f);
    o.w = fmaxf(acc.w * d + bb.w, 0.f);
    (gin ? out1 : out0)[(size_t)node * 32 + c4] = o;
}

__global__ void k_gather_gcn(const unsigned short* __restrict__ t, const int* __restrict__ rowptr,
                             const int* __restrict__ col, const float* __restrict__ dis,
                             const float4* __restrict__ bias, float4* __restrict__ out, int N) {
    int i = blockIdx.x * blockDim.x + threadIdx.x;
    int node = i >> 5, c4 = i & 31;
    if (node >= N) return;
    int s = rowptr[node], e = rowptr[node + 1];
    float4 acc = ld_bf4(t + (size_t)node * DIMC + c4 * 4);
    int k = s;
    for (; k + 4 <= e; k += 4) {
        int c0 = col[k], c1 = col[k + 1], c2 = col[k + 2], c3 = col[k + 3];
        float4 v0 = ld_bf4(t + (size_t)c0 * DIMC + c4 * 4);
        float4 v1 = ld_bf4(t + (size_t)c1 * DIMC + c4 * 4);
        float4 v2 = ld_bf4(t + (size_t)c2 * DIMC + c4 * 4);
        float4 v3 = ld_bf4(t + (size_t)c3 * DIMC + c4 * 4);
        acc.x += (v0.x + v1.x) + (v2.x + v3.x);
        acc.y += (v0.y + v1.y) + (v2.y + v3.y);
        acc.z += (v0.z + v1.z) + (v2.z + v3.z);
        acc.w += (v0.w + v1.w) + (v2.w + v3.w);
    }
    for (; k < e; ++k) {
        float4 v = ld_bf4(t + (size_t)col[k] * DIMC + c4 * 4);
        acc.x += v.x; acc.y += v.y; acc.z += v.z; acc.w += v.w;
    }
    float d = dis[node];
    float4 b = bias[c4];
    float4 o;
    o.x = fmaxf(acc.x * d + b.x, 0.f);
    o.y = fmaxf(acc.y * d + b.y, 0.f);
    o.z = fmaxf(acc.z * d + b.z, 0.f);
    o.w = fmaxf(acc.w * d + b.w, 0.f);
    out[(size_t)node * 32 + c4] = o;
}

__global__ void k_gather_gin(const unsigned short* __restrict__ t, const int* __restrict__ rowptr,
                             const int* __restrict__ col, const float4* __restrict__ bias,
                             float4* __restrict__ out, int N) {
    int i = blockIdx.x * blockDim.x + threadIdx.x;
    int node = i >> 5, c4 = i & 31;
    if (node >= N) return;
    int s = rowptr[node], e = rowptr[node + 1];
    float4 acc = ld_bf4(t + (size_t)node * DIMC + c4 * 4);
    int k = s;
    for (; k + 4 <= e; k += 4) {
        int c0 = col[k], c1 = col[k + 1], c2 = col[k + 2], c3 = col[k + 3];
        float4 v0 = ld_bf4(t + (size_t)c0 * DIMC + c4 * 4);
        float4 v1 = ld_bf4(t + (size_t)c1 * DIMC + c4 * 4);
        float4 v2 = ld_bf4(t + (size_t)c2 * DIMC + c4 * 4);
        float4 v3 = ld_bf4(t + (size_t)c3 * DIMC + c4 * 4);
        acc.x += (v0.x + v1.x) + (v2.x + v3.x);
        acc.y += (v0.y + v1.y) + (v2.y + v3.y);
        acc.z += (v0.z + v1.z) + (v2.z + v3.z);
        acc.w += (v0.w + v1.w) + (v2.w + v3.w);
    }
    for (; k < e; ++k) {
        float4 v = ld_bf4(t + (size_t)col[k] * DIMC + c4 * 4);
        acc.x += v.x; acc.y += v.y; acc.z += v.z; acc.w += v.w;
    }
    float4 b = bias[c4];
    float4 o;
    o.x = fmaxf(acc.x + b.x, 0.f);
    o.y = fmaxf(acc.y + b.y, 0.f);
    o.z = fmaxf(acc.z + b.z, 0.f);
    o.w = fmaxf(acc.w + b.w, 0.f);
    out[(size_t)node * 32 + c4] = o;
}

// ---------------- segment max (fp32) ----------------

__global__ void k_segmax_gin_all(const float* __restrict__ h0, const float* __restrict__ h1,
                                 const float* __restrict__ h2, const float* __restrict__ coef,
                                 const int* __restrict__ start, float* __restrict__ out) {
    int g = blockIdx.x, c = threadIdx.x;
    float s0 = coef[c],       t0 = coef[128 + c];
    float s1 = coef[256 + c], t1 = coef[384 + c];
    float s2 = coef[512 + c], t2 = coef[640 + c];
    int s = start[g], e = start[g + 1];
    float m0 = -INFINITY, m1 = -INFINITY, m2 = -INFINITY, mm = -INFINITY, me = -INFINITY;
    for (int n = s; n < e; ++n) {
        size_t idx = (size_t)n * DIMC + c;
        float a0 = fmaf(h0[idx], s0, t0);
        float a1 = fmaf(h1[idx], s1, t1);
        float a2 = fmaf(h2[idx], s2, t2);
        m0 = fmaxf(m0, a0); m1 = fmaxf(m1, a1); m2 = fmaxf(m2, a2);
        mm = fmaxf(mm, a0 * a1 * a2);
        me = fmaxf(me, a0 + a1 + a2);
    }
    size_t o = (size_t)g * REPW + c;
    out[o]            = m0;
    out[o + 1 * DIMC] = m1;
    out[o + 2 * DIMC] = m2;
    out[o + 3 * DIMC] = mm;
    out[o + 4 * DIMC] = me;
}

__global__ void k_segmax_gcn(const float* __restrict__ G1, const float* __restrict__ G2,
                             const int* __restrict__ start, float* __restrict__ out) {
    int g = blockIdx.x, c = threadIdx.x;
    int s = start[g], e = start[g + 1];
    float m1 = -INFINITY, m2 = -INFINITY, ma = -INFINITY, mm = -INFINITY;
    for (int n = s; n < e; ++n) {
        float a = G1[(size_t)n * DIMC + c], b = G2[(size_t)n * DIMC + c];
        m1 = fmaxf(m1, a); m2 = fmaxf(m2, b);
        ma = fmaxf(ma, a + b); mm = fmaxf(mm, a * b);
    }
    size_t o = (size_t)g * REPW + c;
    out[o + 5 * DIMC] = m1;
    out[o + 6 * DIMC] = m2;
    out[o + 7 * DIMC] = ma;
    out[o + 8 * DIMC] = mm;
}

// ---------------- launch ----------------

extern "C" void kernel_launch(void* const* d_in, const int* in_sizes, int n_in,
                              void* d_out, int out_size, void* d_ws, size_t ws_size,
                              hipStream_t stream) {
    const float* x       = (const float*)d_in[0];
    const int*   ei      = (const int*)d_in[1];
    const int*   batch   = (const int*)d_in[2];
    const float* gcn1_W  = (const float*)d_in[4];
    const float* gcn1_b  = (const float*)d_in[5];
    const float* gcn2_W  = (const float*)d_in[6];
    const float* gcn2_b  = (const float*)d_in[7];
    const float* gin0_w1 = (const float*)d_in[8];
    const float* gin0_b1 = (const float*)d_in[9];
    const float* gin0_w2 = (const float*)d_in[10];
    const float* gin0_b2 = (const float*)d_in[11];
    const float* gin_w1  = (const float*)d_in[12];
    const float* gin_b1  = (const float*)d_in[13];
    const float* gin_w2  = (const float*)d_in[14];
    const float* gin_b2  = (const float*)d_in[15];
    const float* bn_g    = (const float*)d_in[16];
    const float* bn_b    = (const float*)d_in[17];
    float* out = (float*)d_out;

    const int N = in_sizes[0] / FINC;   // 100000
    const int E = in_sizes[1] / 2;      // 400000
    const int G = out_size / REPW;      // 2500
    const int* srcv = ei;
    const int* dstv = ei + E;

    // Workspace (~263 MB, proven-safe). x96 aliases h1 (x dead before h1 written).
    // GEMM A-DMA may read up to 128 rows past N; all A-input buffers are followed
    // by other allocs -> in-bounds.
    char* ws = (char*)d_ws;
    size_t off = 0;
    auto alloc = [&](size_t bytes) { char* p = ws + off; off += (bytes + 255) & ~(size_t)255; return p; };
    int*   cnt     = (int*)alloc((size_t)N * 4);
    int*   rowptr  = (int*)alloc(((size_t)N + 1) * 4);
    int*   cursor  = (int*)alloc((size_t)N * 4);
    int*   col     = (int*)alloc((size_t)E * 4);
    float* dis     = (float*)alloc((size_t)N * 4);
    float* bnsum   = (float*)alloc(768 * 4);
    float* coef    = (float*)alloc(768 * 4);
    float* cvec    = (float*)alloc(128 * 4);
    int*   start   = (int*)alloc(((size_t)G + 1) * 4);
    int*   tileSum = (int*)alloc(256 * 4);
    int*   tileOff = (int*)alloc(256 * 4);
    const size_t o96 = (size_t)128 * 96, o128 = (size_t)128 * 128;
    const size_t wtElems = 2 * o96 + 6 * o128;
    unsigned short* whi  = (unsigned short*)alloc(wtElems * 2);
    unsigned short* wlo  = (unsigned short*)alloc(wtElems * 2);
    unsigned short* fwhi = (unsigned short*)alloc(o128 * 2);
    unsigned short* fwlo = (unsigned short*)alloc(o128 * 2);
    const size_t fbytes = (size_t)N * DIMC * 4;
    float* bufZ = (float*)alloc(fbytes);
    float* h0   = (float*)alloc(fbytes);
    float* h1   = (float*)alloc(fbytes);   // hosts x96 early
    float* h2   = (float*)alloc(fbytes);
    unsigned short* tb0 = (unsigned short*)alloc((size_t)N * DIMC * 2);
    unsigned short* tb1 = (unsigned short*)alloc((size_t)N * DIMC * 2);
    float* x96  = h1;
    (void)ws_size; (void)n_in;

    const size_t woff[8] = {0, o96, 2 * o96, 2 * o96 + o128, 2 * o96 + 2 * o128,
                            2 * o96 + 3 * o128, 2 * o96 + 4 * o128, 2 * o96 + 5 * o128};
    // order: gcn1, gin0_w1, gcn2, gin0_w2, gin_w1[0], gin_w1[1], gin_w2[0], gin_w2[1]

    const int T = 256;
    auto cdiv = [](long a, long b) { return (int)((a + b - 1) / b); };
    const int gemmGrid = cdiv(N, 128);
    const int gatherGrid = cdiv((long)N * 32, T);
    const int nTiles = cdiv(N, SCAN_TILE);
    const float invN = 1.0f / (float)N;

    // ---- CSR build + norms + graph bounds + weight split + x pad ----
    k_fill_int<<<cdiv(N, T), T, 0, stream>>>(cnt, 0, N);
    k_count<<<cdiv(E, T), T, 0, stream>>>(dstv, cnt, E);
    k_tilesum<<<nTiles, T, 0, stream>>>(cnt, tileSum, N);
    k_tilescan<<<1, T, 0, stream>>>(tileSum, tileOff, rowptr, nTiles, N);
    k_tileemit<<<nTiles, T, 0, stream>>>(cnt, tileOff, rowptr, cursor, dis, N);
    k_scatter<<<cdiv(E, T), T, 0, stream>>>(srcv, dstv, cursor, col, E);
    k_bounds<<<cdiv(G + 1, T), T, 0, stream>>>(batch, start, N, G);
    k_fill<<<3, T, 0, stream>>>(bnsum, 0.f, 768);
    {
        dim3 g(64, 8);
        k_cvt_w<<<g, T, 0, stream>>>(gcn1_W, gin0_w1, gcn2_W, gin0_w2,
                                     gin_w1, gin_w1 + o128, gin_w2, gin_w2 + o128, whi, wlo);
    }
    k_pad_x<<<cdiv((long)N * 24, T), T, 0, stream>>>(x, x96, N);

    // ---- fused x-GEMM: GCN t1 (scaled, bf16) -> tb0, GIN t0 (bf16) -> tb1 ----
    k_gemm_x2<<<gemmGrid, T, 0, stream>>>(x96, whi + woff[0], wlo + woff[0],
                                          whi + woff[1], wlo + woff[1],
                                          dis, tb0, tb1, N);

    // ---- fused gathers: g1 (tb0 -> bufZ) and z0 (tb1 -> h0) ----
    k_gather2<<<2 * gatherGrid, T, 0, stream>>>(tb0, dis,
                                                (const float4*)gcn1_b, (float4*)bufZ,
                                                tb1, (const float4*)gin0_b1,
                                                (float4*)h0, rowptr, col, N, gatherGrid);

    // ---- fused dual GEMM: t2 = g1@gcn2 (scaled, bf16) -> tb0; h0 = relu(z0@gin0_w2+b)+stats ----
    k_gemm_d2<<<gemmGrid, T, 0, stream>>>(bufZ, whi + woff[2], wlo + woff[2], dis, tb0,
                                          h0, whi + woff[3], wlo + woff[3], gin0_b2,
                                          bnsum, h0, N);

    // ---- GCN tail ----
    k_gather_gcn<<<gatherGrid, T, 0, stream>>>(tb0, rowptr, col, dis,
                                               (const float4*)gcn2_b, (float4*)h2, N);     // g2 -> h2
    k_segmax_gcn<<<G, DIMC, 0, stream>>>(bufZ, h2, start, out);                            // groups 5..8

    // ---- GIN layer 1 prep ----
    k_bn_coef<<<1, DIMC, 0, stream>>>(bnsum, bn_g, bn_b, coef, invN);
    k_fold_w<<<DIMC, DIMC, 0, stream>>>(gin_w1, coef, fwhi, fwlo, cvec);

    // ---- GIN layer 1 (x96 in h1 dead from here) ----
    k_gemm_c<128, false, true><<<gemmGrid, T, 0, stream>>>(h0, fwhi, fwlo,
                                                           cvec, nullptr, nullptr, tb0, N, 0);
    k_gather_gin<<<gatherGrid, T, 0, stream>>>(tb0, rowptr, col,
                                               (const float4*)gin_b1, (float4*)bufZ, N);
    k_gemm_c<128, true, false><<<gemmGrid, T, 0, stream>>>(bufZ, whi + woff[6], wlo + woff[6],
                                                           gin_b2, nullptr, bnsum + 256, h1, N, 1);
    k_bn_coef<<<1, DIMC, 0, stream>>>(bnsum + 256, bn_g + DIMC, bn_b + DIMC, coef + 256, invN);
    k_fold_w<<<DIMC, DIMC, 0, stream>>>(gin_w1 + o128, coef + 256, fwhi, fwlo, cvec);

    // ---- GIN layer 2 (h2's g2 role ended at segmax; becomes final h2 plane) ----
    k_gemm_c<128, false, true><<<gemmGrid, T, 0, stream>>>(h1, fwhi, fwlo,
                                                           cvec, nullptr, nullptr, tb0, N, 0);
    k_gather_gin<<<gatherGrid, T, 0, stream>>>(tb0, rowptr, col,
                                               (const float4*)(gin_b1 + DIMC), (float4*)bufZ, N);
    k_gemm_c<128, true, false><<<gemmGrid, T, 0, stream>>>(bufZ, whi + woff[7], wlo + woff[7],
                                                           gin_b2 + DIMC, nullptr, bnsum + 512, h2, N, 1);
    k_bn_coef<<<1, DIMC, 0, stream>>>(bnsum + 512, bn_g + 2 * DIMC, bn_b + 2 * DIMC, coef + 512, invN);

    k_segmax_gin_all<<<G, DIMC, 0, stream>>>(h0, h1, h2, coef, start, out);                // groups 0..4
}